// Round 8
// baseline (517.736 us; speedup 1.0000x reference)
//
#include <hip/hip_runtime.h>
#include <hip/hip_fp16.h>

#define N_NODES 50000
#define N_EDGES 800000
#define CH 64
#define FT_NODES 32
#define FT_BLKS ((N_NODES + FT_NODES - 1) / FT_NODES)   // 1563
#define BKT_NODES 128
#define NBKT ((N_NODES + BKT_NODES - 1) / BKT_NODES)    // 391
#define ECHUNK ((N_EDGES + NBKT - 1) / NBKT)            // 2047

static constexpr size_t alignup16(size_t x) { return (x + 15) & ~(size_t)15; }
// ---------------- ws layout (byte offsets, 16B-aligned) ----------------
static const size_t OFF_H    = 0;                                         // N*CH half (6.4 MB)
static const size_t OFF_SSRC = alignup16(OFF_H    + (size_t)N_NODES*CH*2);
static const size_t OFF_SDST = alignup16(OFF_SSRC + (size_t)N_NODES*4);
static const size_t OFF_HIST = alignup16(OFF_SDST + (size_t)N_NODES*4);   // NBKT*NBKT u32 (612 KB)
static const size_t OFF_CB   = alignup16(OFF_HIST + (size_t)NBKT*NBKT*4); // NBKT+1 u32
static const size_t OFF_BUCK = alignup16(OFF_CB   + (size_t)(NBKT+1)*4);  // E u32 (3.2 MB)

// K1: h = x @ W (fp16 out); s_src/s_dst scores; blocks < NBKT also histogram
// their edge chunk by coarse bucket (dst>>7) into LDS -> hist[bin*NBKT+blk].
__global__ __launch_bounds__(256) void k_feat(
        const float* __restrict__ x, const float* __restrict__ W,
        const float* __restrict__ a_src, const float* __restrict__ a_dst,
        const int* __restrict__ edst,
        __half* __restrict__ h, float* __restrict__ ssrc, float* __restrict__ sdst,
        unsigned int* __restrict__ hist) {
    __shared__ float Ws[64 * 64];          // 16 KB
    __shared__ float xs[FT_NODES][68];     // pad 64->68: bank-conflict-free, rows 16B-aligned
    __shared__ unsigned int lh[NBKT];
    const int tid = threadIdx.x;
    const bool do_hist = (blockIdx.x < NBKT);
    if (do_hist)
        for (int j = tid; j < NBKT; j += 256) lh[j] = 0u;
#pragma unroll
    for (int i = 0; i < 16; ++i) Ws[tid + i * 256] = W[tid + i * 256];
    const int n0 = blockIdx.x * FT_NODES;
    const int nvalid = min(FT_NODES, N_NODES - n0);
    const float4* x4 = (const float4*)(x + (size_t)n0 * CH);
    for (int i = tid; i < nvalid * 16; i += 256) {
        const int n = i >> 4, q = i & 15;
        *(float4*)&xs[n][q * 4] = x4[i];
    }
    __syncthreads();
    if (do_hist) {
        const int st = blockIdx.x * ECHUNK;
        const int en = min(st + ECHUNK, N_EDGES);
        for (int i = st + tid; i < en; i += 256)
            atomicAdd(&lh[((unsigned int)edst[i]) >> 7], 1u);
    }
    const int nl = tid >> 3;
    const int g = tid & 7;
    const int c0 = g * 8;
    const int node = n0 + nl;
    if (nl < nvalid) {
        float acc[8] = {0.f, 0.f, 0.f, 0.f, 0.f, 0.f, 0.f, 0.f};
#pragma unroll
        for (int k = 0; k < 64; ++k) {
            const float xv = xs[nl][k];
            const float4 w0 = *(const float4*)&Ws[k * 64 + c0];
            const float4 w1 = *(const float4*)&Ws[k * 64 + c0 + 4];
            acc[0] = fmaf(xv, w0.x, acc[0]);
            acc[1] = fmaf(xv, w0.y, acc[1]);
            acc[2] = fmaf(xv, w0.z, acc[2]);
            acc[3] = fmaf(xv, w0.w, acc[3]);
            acc[4] = fmaf(xv, w1.x, acc[4]);
            acc[5] = fmaf(xv, w1.y, acc[5]);
            acc[6] = fmaf(xv, w1.z, acc[6]);
            acc[7] = fmaf(xv, w1.w, acc[7]);
        }
        __half2 hv[4];
#pragma unroll
        for (int i = 0; i < 4; ++i) hv[i] = __floats2half2_rn(acc[2 * i], acc[2 * i + 1]);
        *(float4*)(h + (size_t)node * CH + c0) = *(float4*)hv;
        float ps = 0.f, pd = 0.f;
#pragma unroll
        for (int i = 0; i < 8; ++i) {
            ps = fmaf(acc[i], a_src[c0 + i], ps);
            pd = fmaf(acc[i], a_dst[c0 + i], pd);
        }
#pragma unroll
        for (int off = 4; off; off >>= 1) {
            ps += __shfl_xor(ps, off);
            pd += __shfl_xor(pd, off);
        }
        if (g == 0) { ssrc[node] = ps; sdst[node] = pd; }
    }
    if (do_hist) {
        __syncthreads();
        for (int j = tid; j < NBKT; j += 256)
            hist[(size_t)j * NBKT + blockIdx.x] = lh[j];
    }
}

// K2: single block: per-bin totals -> exclusive scan -> rewrite hist in place as
// per-(bin,block) base offsets; emit coarse bucket bases cb[0..NBKT].
__global__ __launch_bounds__(512) void k_bases(
        unsigned int* __restrict__ hist, unsigned int* __restrict__ cb) {
    __shared__ unsigned int s[512];
    const int t = threadIdx.x;
    unsigned int total = 0u;
    if (t < NBKT) {
#pragma unroll 8
        for (int b = 0; b < NBKT; ++b) total += hist[(size_t)t * NBKT + b];
    }
    s[t] = total;
    __syncthreads();
#pragma unroll
    for (int off = 1; off < 512; off <<= 1) {
        unsigned int v = (t >= off) ? s[t - off] : 0u;
        __syncthreads();
        s[t] += v;
        __syncthreads();
    }
    if (t < NBKT) {
        unsigned int run = s[t] - total;   // exclusive prefix
        cb[t] = run;
        if (t == NBKT - 1) cb[NBKT] = N_EDGES;
#pragma unroll 4
        for (int b = 0; b < NBKT; ++b) {
            const unsigned int v = hist[(size_t)t * NBKT + b];
            hist[(size_t)t * NBKT + b] = run;
            run += v;
        }
    }
}

// K3: scatter packed records ((dst&127)<<16 | src) into coarse buckets.
// Slot = precomputed (bin,block) base + LDS rank. No global atomics.
__global__ __launch_bounds__(256) void k_scatter_b(
        const int* __restrict__ esrc, const int* __restrict__ edst,
        const unsigned int* __restrict__ hist, unsigned int* __restrict__ buck) {
    __shared__ unsigned int wp[NBKT];
    const int tid = threadIdx.x;
    const int blk = blockIdx.x;
    for (int j = tid; j < NBKT; j += 256) wp[j] = hist[(size_t)j * NBKT + blk];
    __syncthreads();
    const int st = blk * ECHUNK;
    const int en = min(st + ECHUNK, N_EDGES);
    for (int i = st + tid; i < en; i += 256) {
        const unsigned int d = (unsigned int)edst[i];
        const unsigned int rec = ((d & 127u) << 16) | (unsigned int)esrc[i];
        const unsigned int pos = atomicAdd(&wp[d >> 7], 1u);
        buck[pos] = rec;
    }
}

// K4: one block per bucket (128 nodes): LDS f32 accumulator tile; wave=edge,
// lane=channel; w = exp(LeakyReLU(ssrc[s]+sdst[d])) recomputed inline (broadcast
// loads, L2-resident); ds_add_f32 accumulate (2 lanes/bank: conflict-free);
// epilogue: normalize + bias + LeakyReLU(0.3), coalesced out write.
__global__ __launch_bounds__(1024) void k_bucket_agg(
        const unsigned int* __restrict__ buck, const unsigned int* __restrict__ cb,
        const float* __restrict__ ssrc, const float* __restrict__ sdst,
        const __half* __restrict__ h, const float* __restrict__ bias,
        float* __restrict__ out) {
    __shared__ float accL[BKT_NODES * CH];   // 32 KB
    __shared__ float wsumL[BKT_NODES];
    __shared__ float sdL[BKT_NODES];
    const int tid = threadIdx.x;
    const int blk = blockIdx.x;
    const int nbase = blk * BKT_NODES;
    for (int j = tid; j < BKT_NODES * CH; j += 1024) accL[j] = 0.f;
    if (tid < BKT_NODES) {
        wsumL[tid] = 0.f;
        const int node = nbase + tid;
        sdL[tid] = (node < N_NODES) ? sdst[node] : 0.f;
    }
    __syncthreads();
    const int wid = tid >> 6, lane = tid & 63;
    const int st = (int)cb[blk], en = (int)cb[blk + 1];
#pragma unroll 2
    for (int i = st + wid; i < en; i += 16) {
        const unsigned int rec = buck[i];
        const int s = (int)(rec & 0xFFFFu);
        const int dl = (int)(rec >> 16);
        float e = ssrc[s] + sdL[dl];
        e = (e > 0.f) ? e : 0.2f * e;
        const float w = __expf(e);
        const float hv = __half2float(h[(size_t)s * CH + lane]);
        atomicAdd(&accL[dl * CH + lane], w * hv);
        if (lane == 0) atomicAdd(&wsumL[dl], w);
    }
    __syncthreads();
    for (int j = tid; j < BKT_NODES * CH; j += 1024) {
        const int dl = j >> 6, c = j & 63;
        const int node = nbase + dl;
        if (node < N_NODES) {
            const float v = accL[j] / fmaxf(wsumL[dl], 1e-9f) + bias[c];
            out[(size_t)node * CH + c] = (v > 0.f) ? v : 0.3f * v;
        }
    }
}

extern "C" void kernel_launch(void* const* d_in, const int* in_sizes, int n_in,
                              void* d_out, int out_size, void* d_ws, size_t ws_size,
                              hipStream_t stream) {
    const float* x     = (const float*)d_in[0];
    const float* W     = (const float*)d_in[1];
    const float* a_src = (const float*)d_in[2];
    const float* a_dst = (const float*)d_in[3];
    const float* b     = (const float*)d_in[4];
    const int* esrc    = (const int*)d_in[5];
    const int* edst    = (const int*)d_in[6];
    float* out = (float*)d_out;

    char* ws = (char*)d_ws;
    __half* h          = (__half*)(ws + OFF_H);
    float* ssrc        = (float*)(ws + OFF_SSRC);
    float* sdst        = (float*)(ws + OFF_SDST);
    unsigned int* hist = (unsigned int*)(ws + OFF_HIST);
    unsigned int* cb   = (unsigned int*)(ws + OFF_CB);
    unsigned int* buck = (unsigned int*)(ws + OFF_BUCK);

    k_feat<<<FT_BLKS, 256, 0, stream>>>(x, W, a_src, a_dst, edst, h, ssrc, sdst, hist);
    k_bases<<<1, 512, 0, stream>>>(hist, cb);
    k_scatter_b<<<NBKT, 256, 0, stream>>>(esrc, edst, hist, buck);
    k_bucket_agg<<<NBKT, 1024, 0, stream>>>(buck, cb, ssrc, sdst, h, b, out);
}

// Round 9
// 90.932 us; speedup vs baseline: 5.6937x; 5.6937x over previous
//
#include <hip/hip_runtime.h>
#include <hip/hip_fp16.h>

#define N_NODES 50000
#define N_EDGES 800000
#define CH 64
#define FT_NODES 32
#define FT_BLKS ((N_NODES + FT_NODES - 1) / FT_NODES)   // 1563
#define NB 196                                          // coarse buckets = ceil(N/256)
#define CHUNK ((N_EDGES + NB - 1) / NB)                 // 4082 edges per hist/scatter chunk

static constexpr size_t alignup16(size_t x) { return (x + 15) & ~(size_t)15; }
// ---------------- ws layout (byte offsets, 16B-aligned) ----------------
static const size_t OFF_H      = 0;                                          // N*CH half (6.4 MB)
static const size_t OFF_SSRC   = alignup16(OFF_H      + (size_t)N_NODES*CH*2);
static const size_t OFF_SDST   = alignup16(OFF_SSRC   + (size_t)N_NODES*4);
static const size_t OFF_HIST   = alignup16(OFF_SDST   + (size_t)N_NODES*4);  // NB*NB u32 (154 KB)
static const size_t OFF_CB     = alignup16(OFF_HIST   + (size_t)NB*NB*4);    // NB+1 u32
static const size_t OFF_ROWPTR = alignup16(OFF_CB     + (size_t)(NB+1)*4);   // N+1 i32
static const size_t OFF_BUCK   = alignup16(OFF_ROWPTR + (size_t)(N_NODES+4)*4); // E u32 (3.2 MB)
static const size_t OFF_SPERM  = alignup16(OFF_BUCK   + (size_t)N_EDGES*4);  // E u16 (1.6 MB)

// K1: h = x @ W (fp16 out); s_src/s_dst scores; blocks < NB also histogram their
// edge chunk by coarse bucket (dst>>8) into LDS -> hist[bin*NB+blk]. LDS-only atomics.
__global__ __launch_bounds__(256) void k_feat(
        const float* __restrict__ x, const float* __restrict__ W,
        const float* __restrict__ a_src, const float* __restrict__ a_dst,
        const int* __restrict__ edst,
        __half* __restrict__ h, float* __restrict__ ssrc, float* __restrict__ sdst,
        unsigned int* __restrict__ hist) {
    __shared__ float Ws[64 * 64];          // 16 KB
    __shared__ float xs[FT_NODES][68];     // pad 64->68: bank-conflict-free, rows 16B-aligned
    __shared__ unsigned int lh[NB];
    const int tid = threadIdx.x;
    const bool do_hist = (blockIdx.x < NB);
    if (do_hist && tid < NB) lh[tid] = 0u;
#pragma unroll
    for (int i = 0; i < 16; ++i) Ws[tid + i * 256] = W[tid + i * 256];
    const int n0 = blockIdx.x * FT_NODES;
    const int nvalid = min(FT_NODES, N_NODES - n0);
    const float4* x4 = (const float4*)(x + (size_t)n0 * CH);
    for (int i = tid; i < nvalid * 16; i += 256) {
        const int n = i >> 4, q = i & 15;
        *(float4*)&xs[n][q * 4] = x4[i];
    }
    __syncthreads();
    if (do_hist) {
        const int st = blockIdx.x * CHUNK;
        const int en = min(st + CHUNK, N_EDGES);
        for (int i = st + tid; i < en; i += 256)
            atomicAdd(&lh[((unsigned int)edst[i]) >> 8], 1u);
    }
    const int nl = tid >> 3;
    const int g = tid & 7;
    const int c0 = g * 8;
    const int node = n0 + nl;
    if (nl < nvalid) {
        float acc[8] = {0.f, 0.f, 0.f, 0.f, 0.f, 0.f, 0.f, 0.f};
#pragma unroll
        for (int k = 0; k < 64; ++k) {
            const float xv = xs[nl][k];
            const float4 w0 = *(const float4*)&Ws[k * 64 + c0];
            const float4 w1 = *(const float4*)&Ws[k * 64 + c0 + 4];
            acc[0] = fmaf(xv, w0.x, acc[0]);
            acc[1] = fmaf(xv, w0.y, acc[1]);
            acc[2] = fmaf(xv, w0.z, acc[2]);
            acc[3] = fmaf(xv, w0.w, acc[3]);
            acc[4] = fmaf(xv, w1.x, acc[4]);
            acc[5] = fmaf(xv, w1.y, acc[5]);
            acc[6] = fmaf(xv, w1.z, acc[6]);
            acc[7] = fmaf(xv, w1.w, acc[7]);
        }
        __half2 hv[4];
#pragma unroll
        for (int i = 0; i < 4; ++i) hv[i] = __floats2half2_rn(acc[2 * i], acc[2 * i + 1]);
        *(float4*)(h + (size_t)node * CH + c0) = *(float4*)hv;
        float ps = 0.f, pd = 0.f;
#pragma unroll
        for (int i = 0; i < 8; ++i) {
            ps = fmaf(acc[i], a_src[c0 + i], ps);
            pd = fmaf(acc[i], a_dst[c0 + i], pd);
        }
#pragma unroll
        for (int off = 4; off; off >>= 1) {
            ps += __shfl_xor(ps, off);
            pd += __shfl_xor(pd, off);
        }
        if (g == 0) { ssrc[node] = ps; sdst[node] = pd; }
    }
    if (do_hist) {
        __syncthreads();
        if (tid < NB) hist[(size_t)tid * NB + blockIdx.x] = lh[tid];
    }
}

// K2: single block: per-bin totals -> exclusive scan -> rewrite hist in place as
// per-(bin,block) base offsets; emit coarse bucket bases cb[0..NB].
__global__ __launch_bounds__(256) void k_bases(
        unsigned int* __restrict__ hist, unsigned int* __restrict__ cb) {
    __shared__ unsigned int s[256];
    const int t = threadIdx.x;
    unsigned int total = 0u;
    if (t < NB) {
#pragma unroll 8
        for (int b = 0; b < NB; ++b) total += hist[(size_t)t * NB + b];
    }
    s[t] = total;
    __syncthreads();
#pragma unroll
    for (int off = 1; off < 256; off <<= 1) {
        unsigned int v = (t >= off) ? s[t - off] : 0u;
        __syncthreads();
        s[t] += v;
        __syncthreads();
    }
    if (t < NB) {
        unsigned int run = s[t] - total;   // exclusive prefix
        cb[t] = run;
        if (t == NB - 1) cb[NB] = N_EDGES;
#pragma unroll 4
        for (int b = 0; b < NB; ++b) {
            const unsigned int v = hist[(size_t)t * NB + b];
            hist[(size_t)t * NB + b] = run;
            run += v;
        }
    }
}

// K3: scatter packed records ((dst&255)<<16 | src) into coarse buckets.
// Slot = precomputed (bin,block) base + LDS rank. No global atomics.
__global__ __launch_bounds__(256) void k_scatter_b(
        const int* __restrict__ esrc, const int* __restrict__ edst,
        const unsigned int* __restrict__ hist, unsigned int* __restrict__ buck) {
    __shared__ unsigned int wp[NB];
    const int tid = threadIdx.x;
    const int blk = blockIdx.x;
    if (tid < NB) wp[tid] = hist[(size_t)tid * NB + blk];
    __syncthreads();
    const int st = blk * CHUNK;
    const int en = min(st + CHUNK, N_EDGES);
    for (int i = st + tid; i < en; i += 256) {
        const unsigned int d = (unsigned int)edst[i];
        const unsigned int rec = ((d & 255u) << 16) | (unsigned int)esrc[i];
        const unsigned int pos = atomicAdd(&wp[d >> 8], 1u);
        buck[pos] = rec;
    }
}

// K4: one block per coarse bucket: LDS counting sort by dst&255 -> row_ptr + u16 src_perm.
__global__ __launch_bounds__(256) void k_csr(
        const unsigned int* __restrict__ buck, const unsigned int* __restrict__ cb,
        int* __restrict__ row_ptr, unsigned short* __restrict__ src_perm) {
    __shared__ unsigned int cnt[256];
    __shared__ unsigned int s[256];
    __shared__ unsigned int wp[256];
    const int t = threadIdx.x;
    const int blk = blockIdx.x;
    const int start = (int)cb[blk];
    const int end = (int)cb[blk + 1];
    cnt[t] = 0u;
    __syncthreads();
    for (int i = start + t; i < end; i += 256)
        atomicAdd(&cnt[buck[i] >> 16], 1u);
    __syncthreads();
    const unsigned int own = cnt[t];
    s[t] = own;
    __syncthreads();
#pragma unroll
    for (int off = 1; off < 256; off <<= 1) {
        unsigned int v = (t >= off) ? s[t - off] : 0u;
        __syncthreads();
        s[t] += v;
        __syncthreads();
    }
    const unsigned int excl = s[t] - own;
    wp[t] = excl;
    const int node = blk * 256 + t;
    if (node < N_NODES) row_ptr[node] = start + (int)excl;
    if (blk == 0 && t == 0) row_ptr[N_NODES] = N_EDGES;
    __syncthreads();
    for (int i = start + t; i < end; i += 256) {
        const unsigned int rec = buck[i];
        const unsigned int pos = atomicAdd(&wp[rec >> 16], 1u);
        src_perm[start + pos] = (unsigned short)(rec & 0xFFFFu);
    }
}

// K5: per-dst-node CSR gather: w = exp(LeakyReLU(ssrc[s]+sdst[d])) inline,
// register accumulate + shuffle broadcast, normalize, bias, LeakyReLU(0.3).
// One wave per node, lane = channel.
__global__ __launch_bounds__(256) void k_node_agg(
        const unsigned short* __restrict__ src_perm, const int* __restrict__ row_ptr,
        const float* __restrict__ ssrc, const float* __restrict__ sdst,
        const __half* __restrict__ h, const float* __restrict__ b,
        float* __restrict__ out) {
    const int tid = threadIdx.x;
    const int lane = tid & 63;
    const int node = blockIdx.x * 4 + (tid >> 6);
    const int row = row_ptr[node];
    const int deg = row_ptr[node + 1] - row;
    const float sd = sdst[node];
    float acc = 0.f;
    float wsum = 0.f;
    for (int base = 0; base < deg; base += 64) {
        const int j = base + lane;
        int s = 0;
        float w = 0.f;
        if (j < deg) {
            s = (int)src_perm[row + j];
            float e = ssrc[s] + sd;
            e = (e > 0.f) ? e : 0.2f * e;
            w = __expf(e);
        }
        wsum += w;
        const int cnt = min(64, deg - base);
        int j2 = 0;
        for (; j2 + 4 <= cnt; j2 += 4) {
            const float a0 = __shfl(w, j2),     a1 = __shfl(w, j2 + 1);
            const float a2 = __shfl(w, j2 + 2), a3 = __shfl(w, j2 + 3);
            const int s0 = __shfl(s, j2),     s1 = __shfl(s, j2 + 1);
            const int s2 = __shfl(s, j2 + 2), s3 = __shfl(s, j2 + 3);
            const float h0 = __half2float(h[s0 * CH + lane]);
            const float h1 = __half2float(h[s1 * CH + lane]);
            const float h2 = __half2float(h[s2 * CH + lane]);
            const float h3 = __half2float(h[s3 * CH + lane]);
            acc = fmaf(a0, h0, acc);
            acc = fmaf(a1, h1, acc);
            acc = fmaf(a2, h2, acc);
            acc = fmaf(a3, h3, acc);
        }
        for (; j2 < cnt; ++j2) {
            const float a = __shfl(w, j2);
            const int ss = __shfl(s, j2);
            acc = fmaf(a, __half2float(h[ss * CH + lane]), acc);
        }
    }
#pragma unroll
    for (int off = 32; off; off >>= 1) wsum += __shfl_xor(wsum, off);
    acc /= fmaxf(wsum, 1e-9f);
    const float v = acc + b[lane];
    out[(size_t)node * CH + lane] = (v > 0.f) ? v : 0.3f * v;
}

extern "C" void kernel_launch(void* const* d_in, const int* in_sizes, int n_in,
                              void* d_out, int out_size, void* d_ws, size_t ws_size,
                              hipStream_t stream) {
    const float* x     = (const float*)d_in[0];
    const float* W     = (const float*)d_in[1];
    const float* a_src = (const float*)d_in[2];
    const float* a_dst = (const float*)d_in[3];
    const float* b     = (const float*)d_in[4];
    const int* esrc    = (const int*)d_in[5];
    const int* edst    = (const int*)d_in[6];
    float* out = (float*)d_out;

    char* ws = (char*)d_ws;
    __half* h                = (__half*)(ws + OFF_H);
    float* ssrc              = (float*)(ws + OFF_SSRC);
    float* sdst              = (float*)(ws + OFF_SDST);
    unsigned int* hist       = (unsigned int*)(ws + OFF_HIST);
    unsigned int* cb         = (unsigned int*)(ws + OFF_CB);
    int* row_ptr             = (int*)(ws + OFF_ROWPTR);
    unsigned int* buck       = (unsigned int*)(ws + OFF_BUCK);
    unsigned short* src_perm = (unsigned short*)(ws + OFF_SPERM);

    k_feat<<<FT_BLKS, 256, 0, stream>>>(x, W, a_src, a_dst, edst, h, ssrc, sdst, hist);
    k_bases<<<1, 256, 0, stream>>>(hist, cb);
    k_scatter_b<<<NB, 256, 0, stream>>>(esrc, edst, hist, buck);
    k_csr<<<NB, 256, 0, stream>>>(buck, cb, row_ptr, src_perm);
    k_node_agg<<<N_NODES / 4, 256, 0, stream>>>(src_perm, row_ptr, ssrc, sdst, h, b, out);
}

// Round 10
// 89.574 us; speedup vs baseline: 5.7800x; 1.0152x over previous
//
#include <hip/hip_runtime.h>
#include <hip/hip_fp16.h>

#define N_NODES 50000
#define N_EDGES 800000
#define CH 64
#define FT_NODES 32
#define FT_BLKS ((N_NODES + FT_NODES - 1) / FT_NODES)   // 1563
#define NB 196                                          // coarse buckets = ceil(N/256)
#define CHUNK ((N_EDGES + NB - 1) / NB)                 // 4082 edges per chunk
#define MAXIT ((CHUNK + 255) / 256)                     // 16
#define LCAP 6144                                       // k_csr LDS sort capacity (mean 4096, sigma 64)

static constexpr size_t alignup16(size_t x) { return (x + 15) & ~(size_t)15; }
// ---------------- ws layout (byte offsets, 16B-aligned) ----------------
static const size_t OFF_H      = 0;                                          // N*CH half (6.4 MB)
static const size_t OFF_SSRC   = alignup16(OFF_H      + (size_t)N_NODES*CH*2);
static const size_t OFF_SDST   = alignup16(OFF_SSRC   + (size_t)N_NODES*4);
static const size_t OFF_HIST   = alignup16(OFF_SDST   + (size_t)N_NODES*4);  // NB*NB u32, layout [blk][bin]
static const size_t OFF_CB     = alignup16(OFF_HIST   + (size_t)NB*NB*4);    // NB+1 u32
static const size_t OFF_ROWPTR = alignup16(OFF_CB     + (size_t)(NB+1)*4);   // N+1 i32
static const size_t OFF_BUCK   = alignup16(OFF_ROWPTR + (size_t)(N_NODES+4)*4); // E u32 (3.2 MB)
static const size_t OFF_SPERM  = alignup16(OFF_BUCK   + (size_t)N_EDGES*4);  // E u16 (1.6 MB)

// K1: h = x @ W (fp16 out); s_src/s_dst scores; blocks < NB also histogram their
// edge chunk by coarse bucket (dst>>8) into LDS -> hist[blk][bin] (coalesced row write).
__global__ __launch_bounds__(256) void k_feat(
        const float* __restrict__ x, const float* __restrict__ W,
        const float* __restrict__ a_src, const float* __restrict__ a_dst,
        const int* __restrict__ edst,
        __half* __restrict__ h, float* __restrict__ ssrc, float* __restrict__ sdst,
        unsigned int* __restrict__ hist) {
    __shared__ float Ws[64 * 64];          // 16 KB
    __shared__ float xs[FT_NODES][68];     // pad 64->68: bank-conflict-free, rows 16B-aligned
    __shared__ unsigned int lh[NB];
    const int tid = threadIdx.x;
    const bool do_hist = (blockIdx.x < NB);
    if (do_hist && tid < NB) lh[tid] = 0u;
#pragma unroll
    for (int i = 0; i < 16; ++i) Ws[tid + i * 256] = W[tid + i * 256];
    const int n0 = blockIdx.x * FT_NODES;
    const int nvalid = min(FT_NODES, N_NODES - n0);
    const float4* x4 = (const float4*)(x + (size_t)n0 * CH);
    for (int i = tid; i < nvalid * 16; i += 256) {
        const int n = i >> 4, q = i & 15;
        *(float4*)&xs[n][q * 4] = x4[i];
    }
    __syncthreads();
    if (do_hist) {
        const int st = blockIdx.x * CHUNK;
        const int en = min(st + CHUNK, N_EDGES);
        for (int i = st + tid; i < en; i += 256)
            atomicAdd(&lh[((unsigned int)edst[i]) >> 8], 1u);
    }
    const int nl = tid >> 3;
    const int g = tid & 7;
    const int c0 = g * 8;
    const int node = n0 + nl;
    if (nl < nvalid) {
        float acc[8] = {0.f, 0.f, 0.f, 0.f, 0.f, 0.f, 0.f, 0.f};
#pragma unroll
        for (int k = 0; k < 64; ++k) {
            const float xv = xs[nl][k];
            const float4 w0 = *(const float4*)&Ws[k * 64 + c0];
            const float4 w1 = *(const float4*)&Ws[k * 64 + c0 + 4];
            acc[0] = fmaf(xv, w0.x, acc[0]);
            acc[1] = fmaf(xv, w0.y, acc[1]);
            acc[2] = fmaf(xv, w0.z, acc[2]);
            acc[3] = fmaf(xv, w0.w, acc[3]);
            acc[4] = fmaf(xv, w1.x, acc[4]);
            acc[5] = fmaf(xv, w1.y, acc[5]);
            acc[6] = fmaf(xv, w1.z, acc[6]);
            acc[7] = fmaf(xv, w1.w, acc[7]);
        }
        __half2 hv[4];
#pragma unroll
        for (int i = 0; i < 4; ++i) hv[i] = __floats2half2_rn(acc[2 * i], acc[2 * i + 1]);
        *(float4*)(h + (size_t)node * CH + c0) = *(float4*)hv;
        float ps = 0.f, pd = 0.f;
#pragma unroll
        for (int i = 0; i < 8; ++i) {
            ps = fmaf(acc[i], a_src[c0 + i], ps);
            pd = fmaf(acc[i], a_dst[c0 + i], pd);
        }
#pragma unroll
        for (int off = 4; off; off >>= 1) {
            ps += __shfl_xor(ps, off);
            pd += __shfl_xor(pd, off);
        }
        if (g == 0) { ssrc[node] = ps; sdst[node] = pd; }
    }
    if (do_hist) {
        __syncthreads();
        if (tid < NB) hist[(size_t)blockIdx.x * NB + tid] = lh[tid];
    }
}

// K2: single block: per-bin totals (coalesced: thread=bin, iterate blocks) ->
// exclusive scan -> rewrite hist in place as per-(blk,bin) base offsets; emit cb[].
__global__ __launch_bounds__(256) void k_bases(
        unsigned int* __restrict__ hist, unsigned int* __restrict__ cb) {
    __shared__ unsigned int s[256];
    const int t = threadIdx.x;
    unsigned int total = 0u;
    if (t < NB) {
#pragma unroll 4
        for (int b = 0; b < NB; ++b) total += hist[(size_t)b * NB + t];
    }
    s[t] = total;
    __syncthreads();
#pragma unroll
    for (int off = 1; off < 256; off <<= 1) {
        unsigned int v = (t >= off) ? s[t - off] : 0u;
        __syncthreads();
        s[t] += v;
        __syncthreads();
    }
    if (t < NB) {
        unsigned int run = s[t] - total;   // exclusive prefix
        cb[t] = run;
        if (t == NB - 1) cb[NB] = N_EDGES;
#pragma unroll 4
        for (int b = 0; b < NB; ++b) {
            const unsigned int v = hist[(size_t)b * NB + t];
            hist[(size_t)b * NB + t] = run;
            run += v;
        }
    }
}

// K3: scatter records (dst<<16 | src) into coarse buckets. Chunk is first
// counting-sorted into compacted LDS, then streamed out so consecutive lanes
// write consecutive addresses within each (blk,bin) run. No global atomics.
__global__ __launch_bounds__(256) void k_scatter_b(
        const int* __restrict__ esrc, const int* __restrict__ edst,
        const unsigned int* __restrict__ hist, unsigned int* __restrict__ buck) {
    __shared__ unsigned int lcnt[NB];
    __shared__ unsigned int lstart[NB];
    __shared__ unsigned int wbase[NB];
    __shared__ unsigned int ssc[256];
    __shared__ unsigned int lrec[CHUNK];   // 16.3 KB
    const int tid = threadIdx.x;
    const int blk = blockIdx.x;
    if (tid < NB) {
        lcnt[tid] = 0u;
        wbase[tid] = hist[(size_t)blk * NB + tid];   // coalesced row read
    }
    __syncthreads();
    const int st = blk * CHUNK;
    const int en = min(st + CHUNK, N_EDGES);
    const int m = en - st;
    unsigned int rec[MAXIT], rank[MAXIT];
#pragma unroll
    for (int it = 0; it < MAXIT; ++it) {
        const int i = st + it * 256 + tid;
        if (i < en) {
            const unsigned int r = (((unsigned int)edst[i]) << 16) | (unsigned int)esrc[i];
            rec[it] = r;
            rank[it] = atomicAdd(&lcnt[r >> 24], 1u);   // r>>24 == dst>>8
        } else rec[it] = 0xFFFFFFFFu;                    // dst<=49999 -> never matches
    }
    __syncthreads();
    const unsigned int v = (tid < NB) ? lcnt[tid] : 0u;
    ssc[tid] = v;
    __syncthreads();
#pragma unroll
    for (int off = 1; off < 256; off <<= 1) {
        unsigned int u = (tid >= off) ? ssc[tid - off] : 0u;
        __syncthreads();
        ssc[tid] += u;
        __syncthreads();
    }
    if (tid < NB) lstart[tid] = ssc[tid] - v;
    __syncthreads();
#pragma unroll
    for (int it = 0; it < MAXIT; ++it) {
        if (rec[it] != 0xFFFFFFFFu)
            lrec[lstart[rec[it] >> 24] + rank[it]] = rec[it];
    }
    __syncthreads();
    for (int p = tid; p < m; p += 256) {
        const unsigned int r = lrec[p];
        const unsigned int bin = r >> 24;
        buck[wbase[bin] + ((unsigned int)p - lstart[bin])] = r;
    }
}

// K4: one block per coarse bucket: LDS counting sort by dst&255 -> row_ptr;
// sorted src ids staged in LDS then copied out linearly (coalesced).
__global__ __launch_bounds__(256) void k_csr(
        const unsigned int* __restrict__ buck, const unsigned int* __restrict__ cb,
        int* __restrict__ row_ptr, unsigned short* __restrict__ src_perm) {
    __shared__ unsigned int cnt[256];
    __shared__ unsigned int sc[256];
    __shared__ unsigned int wp[256];
    __shared__ unsigned short lsrc[LCAP];   // 12 KB
    const int t = threadIdx.x;
    const int blk = blockIdx.x;
    const int start = (int)cb[blk];
    const int end = (int)cb[blk + 1];
    const int m = end - start;
    cnt[t] = 0u;
    __syncthreads();
    for (int i = start + t; i < end; i += 256)
        atomicAdd(&cnt[(buck[i] >> 16) & 255u], 1u);
    __syncthreads();
    const unsigned int own = cnt[t];
    sc[t] = own;
    __syncthreads();
#pragma unroll
    for (int off = 1; off < 256; off <<= 1) {
        unsigned int v = (t >= off) ? sc[t - off] : 0u;
        __syncthreads();
        sc[t] += v;
        __syncthreads();
    }
    const unsigned int excl = sc[t] - own;
    wp[t] = excl;
    const int node = blk * 256 + t;
    if (node < N_NODES) row_ptr[node] = start + (int)excl;
    if (blk == 0 && t == 0) row_ptr[N_NODES] = N_EDGES;
    __syncthreads();
    if (m <= LCAP) {
        for (int i = start + t; i < end; i += 256) {
            const unsigned int rec = buck[i];
            const unsigned int pos = atomicAdd(&wp[(rec >> 16) & 255u], 1u);
            lsrc[pos] = (unsigned short)(rec & 0xFFFFu);
        }
        __syncthreads();
        for (int p = t; p < m; p += 256)
            src_perm[start + p] = lsrc[p];
    } else {   // statistically unreachable fallback (keeps correctness unconditional)
        for (int i = start + t; i < end; i += 256) {
            const unsigned int rec = buck[i];
            const unsigned int pos = atomicAdd(&wp[(rec >> 16) & 255u], 1u);
            src_perm[start + (int)pos] = (unsigned short)(rec & 0xFFFFu);
        }
    }
}

// K5: per-dst-node CSR gather: w = exp(LeakyReLU(ssrc[s]+sdst[d])) inline,
// register accumulate + shuffle broadcast (8 gathers in flight), normalize,
// bias, LeakyReLU(0.3). One wave per node, lane = channel.
__global__ __launch_bounds__(256) void k_node_agg(
        const unsigned short* __restrict__ src_perm, const int* __restrict__ row_ptr,
        const float* __restrict__ ssrc, const float* __restrict__ sdst,
        const __half* __restrict__ h, const float* __restrict__ b,
        float* __restrict__ out) {
    const int tid = threadIdx.x;
    const int lane = tid & 63;
    const int node = blockIdx.x * 4 + (tid >> 6);
    const int row = row_ptr[node];
    const int deg = row_ptr[node + 1] - row;
    const float sd = sdst[node];
    float acc = 0.f;
    float wsum = 0.f;
    for (int base = 0; base < deg; base += 64) {
        const int j = base + lane;
        int s = 0;
        float w = 0.f;
        if (j < deg) {
            s = (int)src_perm[row + j];
            float e = ssrc[s] + sd;
            e = (e > 0.f) ? e : 0.2f * e;
            w = __expf(e);
        }
        wsum += w;
        const int cnt = min(64, deg - base);
        int j2 = 0;
        for (; j2 + 8 <= cnt; j2 += 8) {
            float a[8]; int si[8]; float hv[8];
#pragma unroll
            for (int q = 0; q < 8; ++q) { a[q] = __shfl(w, j2 + q); si[q] = __shfl(s, j2 + q); }
#pragma unroll
            for (int q = 0; q < 8; ++q) hv[q] = __half2float(h[(size_t)si[q] * CH + lane]);
#pragma unroll
            for (int q = 0; q < 8; ++q) acc = fmaf(a[q], hv[q], acc);
        }
        for (; j2 + 4 <= cnt; j2 += 4) {
            float a[4]; int si[4]; float hv[4];
#pragma unroll
            for (int q = 0; q < 4; ++q) { a[q] = __shfl(w, j2 + q); si[q] = __shfl(s, j2 + q); }
#pragma unroll
            for (int q = 0; q < 4; ++q) hv[q] = __half2float(h[(size_t)si[q] * CH + lane]);
#pragma unroll
            for (int q = 0; q < 4; ++q) acc = fmaf(a[q], hv[q], acc);
        }
        for (; j2 < cnt; ++j2) {
            const float a = __shfl(w, j2);
            const int ss = __shfl(s, j2);
            acc = fmaf(a, __half2float(h[(size_t)ss * CH + lane]), acc);
        }
    }
#pragma unroll
    for (int off = 32; off; off >>= 1) wsum += __shfl_xor(wsum, off);
    acc /= fmaxf(wsum, 1e-9f);
    const float v = acc + b[lane];
    out[(size_t)node * CH + lane] = (v > 0.f) ? v : 0.3f * v;
}

extern "C" void kernel_launch(void* const* d_in, const int* in_sizes, int n_in,
                              void* d_out, int out_size, void* d_ws, size_t ws_size,
                              hipStream_t stream) {
    const float* x     = (const float*)d_in[0];
    const float* W     = (const float*)d_in[1];
    const float* a_src = (const float*)d_in[2];
    const float* a_dst = (const float*)d_in[3];
    const float* b     = (const float*)d_in[4];
    const int* esrc    = (const int*)d_in[5];
    const int* edst    = (const int*)d_in[6];
    float* out = (float*)d_out;

    char* ws = (char*)d_ws;
    __half* h                = (__half*)(ws + OFF_H);
    float* ssrc              = (float*)(ws + OFF_SSRC);
    float* sdst              = (float*)(ws + OFF_SDST);
    unsigned int* hist       = (unsigned int*)(ws + OFF_HIST);
    unsigned int* cb         = (unsigned int*)(ws + OFF_CB);
    int* row_ptr             = (int*)(ws + OFF_ROWPTR);
    unsigned int* buck       = (unsigned int*)(ws + OFF_BUCK);
    unsigned short* src_perm = (unsigned short*)(ws + OFF_SPERM);

    k_feat<<<FT_BLKS, 256, 0, stream>>>(x, W, a_src, a_dst, edst, h, ssrc, sdst, hist);
    k_bases<<<1, 256, 0, stream>>>(hist, cb);
    k_scatter_b<<<NB, 256, 0, stream>>>(esrc, edst, hist, buck);
    k_csr<<<NB, 256, 0, stream>>>(buck, cb, row_ptr, src_perm);
    k_node_agg<<<N_NODES / 4, 256, 0, stream>>>(src_perm, row_ptr, ssrc, sdst, h, b, out);
}

// Round 11
// 82.092 us; speedup vs baseline: 6.3068x; 1.0911x over previous
//
#include <hip/hip_runtime.h>
#include <hip/hip_fp16.h>

#define N_NODES 50000
#define N_EDGES 800000
#define CH 64
#define FT_NODES 32
#define FT_BLKS ((N_NODES + FT_NODES - 1) / FT_NODES)   // 1563
#define NB 782                                          // bins = ceil(N/64) (64-node buckets)
#define NCHK 784                                        // edge chunks (also hist blocks in k_feat)
#define ECHUNK ((N_EDGES + NCHK - 1) / NCHK)            // 1021
#define LCAP 2048                                       // k_csr LDS stage cap (mean 1024, sigma 32)

static constexpr size_t alignup16(size_t x) { return (x + 15) & ~(size_t)15; }
// ---------------- ws layout (byte offsets, 16B-aligned) ----------------
static const size_t OFF_H      = 0;                                          // N*CH half (6.4 MB)
static const size_t OFF_SSRC   = alignup16(OFF_H      + (size_t)N_NODES*CH*2);
static const size_t OFF_SDST   = alignup16(OFF_SSRC   + (size_t)N_NODES*4);
static const size_t OFF_HIST   = alignup16(OFF_SDST   + (size_t)N_NODES*4);  // NCHK*NB u32 [chunk][bin] (2.45 MB)
static const size_t OFF_BTOT   = alignup16(OFF_HIST   + (size_t)NCHK*NB*4);  // NB u32
static const size_t OFF_CB     = alignup16(OFF_BTOT   + (size_t)NB*4);       // NB+1 u32
static const size_t OFF_ROWPTR = alignup16(OFF_CB     + (size_t)(NB+1)*4);   // N+1 i32
static const size_t OFF_BUCK   = alignup16(OFF_ROWPTR + (size_t)(N_NODES+4)*4); // E u32 (3.2 MB)
static const size_t OFF_SPERM  = alignup16(OFF_BUCK   + (size_t)N_EDGES*4);  // E u16 (1.6 MB)

// K1: h = x @ W (fp16 out); s_src/s_dst scores; blocks < NCHK also histogram their
// edge chunk by bin (dst>>6) into LDS -> hist[blk][bin] (coalesced row write).
__global__ __launch_bounds__(256) void k_feat(
        const float* __restrict__ x, const float* __restrict__ W,
        const float* __restrict__ a_src, const float* __restrict__ a_dst,
        const int* __restrict__ edst,
        __half* __restrict__ h, float* __restrict__ ssrc, float* __restrict__ sdst,
        unsigned int* __restrict__ hist) {
    __shared__ float Ws[64 * 64];          // 16 KB
    __shared__ float xs[FT_NODES][68];     // pad 64->68: bank-conflict-free, rows 16B-aligned
    __shared__ unsigned int lh[NB];        // 3.1 KB
    const int tid = threadIdx.x;
    const bool do_hist = (blockIdx.x < NCHK);
    if (do_hist)
        for (int j = tid; j < NB; j += 256) lh[j] = 0u;
#pragma unroll
    for (int i = 0; i < 16; ++i) Ws[tid + i * 256] = W[tid + i * 256];
    const int n0 = blockIdx.x * FT_NODES;
    const int nvalid = min(FT_NODES, N_NODES - n0);
    const float4* x4 = (const float4*)(x + (size_t)n0 * CH);
    for (int i = tid; i < nvalid * 16; i += 256) {
        const int n = i >> 4, q = i & 15;
        *(float4*)&xs[n][q * 4] = x4[i];
    }
    __syncthreads();
    if (do_hist) {
        const int st = blockIdx.x * ECHUNK;
        const int en = min(st + ECHUNK, N_EDGES);
        for (int i = st + tid; i < en; i += 256)
            atomicAdd(&lh[((unsigned int)edst[i]) >> 6], 1u);
    }
    const int nl = tid >> 3;
    const int g = tid & 7;
    const int c0 = g * 8;
    const int node = n0 + nl;
    if (nl < nvalid) {
        float acc[8] = {0.f, 0.f, 0.f, 0.f, 0.f, 0.f, 0.f, 0.f};
#pragma unroll
        for (int k = 0; k < 64; ++k) {
            const float xv = xs[nl][k];
            const float4 w0 = *(const float4*)&Ws[k * 64 + c0];
            const float4 w1 = *(const float4*)&Ws[k * 64 + c0 + 4];
            acc[0] = fmaf(xv, w0.x, acc[0]);
            acc[1] = fmaf(xv, w0.y, acc[1]);
            acc[2] = fmaf(xv, w0.z, acc[2]);
            acc[3] = fmaf(xv, w0.w, acc[3]);
            acc[4] = fmaf(xv, w1.x, acc[4]);
            acc[5] = fmaf(xv, w1.y, acc[5]);
            acc[6] = fmaf(xv, w1.z, acc[6]);
            acc[7] = fmaf(xv, w1.w, acc[7]);
        }
        __half2 hv[4];
#pragma unroll
        for (int i = 0; i < 4; ++i) hv[i] = __floats2half2_rn(acc[2 * i], acc[2 * i + 1]);
        *(float4*)(h + (size_t)node * CH + c0) = *(float4*)hv;
        float ps = 0.f, pd = 0.f;
#pragma unroll
        for (int i = 0; i < 8; ++i) {
            ps = fmaf(acc[i], a_src[c0 + i], ps);
            pd = fmaf(acc[i], a_dst[c0 + i], pd);
        }
#pragma unroll
        for (int off = 4; off; off >>= 1) {
            ps += __shfl_xor(ps, off);
            pd += __shfl_xor(pd, off);
        }
        if (g == 0) { ssrc[node] = ps; sdst[node] = pd; }
    }
    if (do_hist) {
        __syncthreads();
        for (int j = tid; j < NB; j += 256)
            hist[(size_t)blockIdx.x * NB + j] = lh[j];
    }
}

// K2: per-bin totals: block b sums hist[*][b] (strided reads, L2-hit).
__global__ __launch_bounds__(256) void k_bintot(
        const unsigned int* __restrict__ hist, unsigned int* __restrict__ bintot) {
    __shared__ unsigned int red[256];
    const int t = threadIdx.x, b = blockIdx.x;
    unsigned int v = 0u;
    for (int c = t; c < NCHK; c += 256) v += hist[(size_t)c * NB + b];
    red[t] = v;
    __syncthreads();
#pragma unroll
    for (int off = 128; off; off >>= 1) {
        if (t < off) red[t] += red[t + off];
        __syncthreads();
    }
    if (t == 0) bintot[b] = red[0];
}

// K3: block b: cb[b] = sum(bintot[0..b)) by parallel reduce; exclusive-scan
// column b of hist in LDS (adding cb[b]) -> per-(chunk,bin) base offsets.
__global__ __launch_bounds__(256) void k_rewrite(
        const unsigned int* __restrict__ bintot, unsigned int* __restrict__ hist,
        unsigned int* __restrict__ cb) {
    __shared__ unsigned int lcol[NCHK];    // 3.1 KB
    __shared__ unsigned int red[256];
    __shared__ unsigned int sc[256];
    const int t = threadIdx.x, b = blockIdx.x;
    unsigned int v = 0u;
    for (int j = t; j < b; j += 256) v += bintot[j];
    red[t] = v;
    for (int c = t; c < NCHK; c += 256) lcol[c] = hist[(size_t)c * NB + b];
    __syncthreads();
#pragma unroll
    for (int off = 128; off; off >>= 1) {
        if (t < off) red[t] += red[t + off];
        __syncthreads();
    }
    const unsigned int cbb = red[0];
    if (t == 0) { cb[b] = cbb; if (b == NB - 1) cb[NB] = N_EDGES; }
    // scan 784 = 196 threads x 4 contiguous
    unsigned int part = 0u;
    const int c0 = 4 * t;
    if (t < 196) {
#pragma unroll
        for (int q = 0; q < 4; ++q) part += lcol[c0 + q];
    }
    sc[t] = part;
    __syncthreads();
#pragma unroll
    for (int off = 1; off < 256; off <<= 1) {
        unsigned int u = (t >= off) ? sc[t - off] : 0u;
        __syncthreads();
        sc[t] += u;
        __syncthreads();
    }
    if (t < 196) {
        unsigned int run = cbb + sc[t] - part;
#pragma unroll
        for (int q = 0; q < 4; ++q) {
            const unsigned int tmp = lcol[c0 + q];
            lcol[c0 + q] = run;
            run += tmp;
        }
    }
    __syncthreads();
    for (int c = t; c < NCHK; c += 256) hist[(size_t)c * NB + b] = lcol[c];
}

// K4: direct scatter (dst<<16|src) via LDS rank counters + precomputed bases.
// 784 blocks (3/CU). Random 4B writes are L2-absorbed (verified r9->r10).
__global__ __launch_bounds__(256) void k_scatter(
        const int* __restrict__ esrc, const int* __restrict__ edst,
        const unsigned int* __restrict__ hist, unsigned int* __restrict__ buck) {
    __shared__ unsigned int wp[NB];
    const int t = threadIdx.x, blk = blockIdx.x;
    for (int j = t; j < NB; j += 256) wp[j] = hist[(size_t)blk * NB + j];
    __syncthreads();
    const int st = blk * ECHUNK;
    const int en = min(st + ECHUNK, N_EDGES);
    for (int i = st + t; i < en; i += 256) {
        const unsigned int d = (unsigned int)edst[i];
        const unsigned int pos = atomicAdd(&wp[d >> 6], 1u);
        buck[pos] = (d << 16) | (unsigned int)esrc[i];
    }
}

// K5: one block per 64-node bucket: count by dst&63, wave-shfl scan -> row_ptr;
// sort src ids into LDS, coalesced copy-out. 782 blocks (3/CU).
__global__ __launch_bounds__(256) void k_csr(
        const unsigned int* __restrict__ buck, const unsigned int* __restrict__ cb,
        int* __restrict__ row_ptr, unsigned short* __restrict__ src_perm) {
    __shared__ unsigned int cnt[64];
    __shared__ unsigned int wp[64];
    __shared__ unsigned short lsrc[LCAP];
    const int t = threadIdx.x, blk = blockIdx.x;
    const int start = (int)cb[blk];
    const int end = (int)cb[blk + 1];
    const int m = end - start;
    if (t < 64) cnt[t] = 0u;
    __syncthreads();
    for (int i = start + t; i < end; i += 256)
        atomicAdd(&cnt[(buck[i] >> 16) & 63u], 1u);
    __syncthreads();
    if (t < 64) {
        const unsigned int own = cnt[t];
        unsigned int incl = own;
#pragma unroll
        for (int d = 1; d < 64; d <<= 1) {
            const unsigned int v = __shfl_up(incl, d);
            if (t >= d) incl += v;
        }
        const unsigned int excl = incl - own;
        wp[t] = excl;
        const int node = blk * 64 + t;
        if (node <= N_NODES) row_ptr[node] = start + (int)excl;  // node==N -> E (blk 781)
    }
    __syncthreads();
    if (m <= LCAP) {
        for (int i = start + t; i < end; i += 256) {
            const unsigned int rec = buck[i];
            const unsigned int pos = atomicAdd(&wp[(rec >> 16) & 63u], 1u);
            lsrc[pos] = (unsigned short)(rec & 0xFFFFu);
        }
        __syncthreads();
        for (int p = t; p < m; p += 256)
            src_perm[start + p] = lsrc[p];
    } else {   // statistically unreachable fallback
        for (int i = start + t; i < end; i += 256) {
            const unsigned int rec = buck[i];
            const unsigned int pos = atomicAdd(&wp[(rec >> 16) & 63u], 1u);
            src_perm[start + (int)pos] = (unsigned short)(rec & 0xFFFFu);
        }
    }
}

// K6: per-dst-node CSR gather: w = exp(LeakyReLU(ssrc[s]+sdst[d])) inline,
// register accumulate + shuffle broadcast (8 gathers in flight), normalize,
// bias, LeakyReLU(0.3). One wave per node, lane = channel.
__global__ __launch_bounds__(256) void k_node_agg(
        const unsigned short* __restrict__ src_perm, const int* __restrict__ row_ptr,
        const float* __restrict__ ssrc, const float* __restrict__ sdst,
        const __half* __restrict__ h, const float* __restrict__ b,
        float* __restrict__ out) {
    const int tid = threadIdx.x;
    const int lane = tid & 63;
    const int node = blockIdx.x * 4 + (tid >> 6);
    const int row = row_ptr[node];
    const int deg = row_ptr[node + 1] - row;
    const float sd = sdst[node];
    float acc = 0.f;
    float wsum = 0.f;
    for (int base = 0; base < deg; base += 64) {
        const int j = base + lane;
        int s = 0;
        float w = 0.f;
        if (j < deg) {
            s = (int)src_perm[row + j];
            float e = ssrc[s] + sd;
            e = (e > 0.f) ? e : 0.2f * e;
            w = __expf(e);
        }
        wsum += w;
        const int cnt = min(64, deg - base);
        int j2 = 0;
        for (; j2 + 8 <= cnt; j2 += 8) {
            float a[8]; int si[8]; float hv[8];
#pragma unroll
            for (int q = 0; q < 8; ++q) { a[q] = __shfl(w, j2 + q); si[q] = __shfl(s, j2 + q); }
#pragma unroll
            for (int q = 0; q < 8; ++q) hv[q] = __half2float(h[(size_t)si[q] * CH + lane]);
#pragma unroll
            for (int q = 0; q < 8; ++q) acc = fmaf(a[q], hv[q], acc);
        }
        for (; j2 + 4 <= cnt; j2 += 4) {
            float a[4]; int si[4]; float hv[4];
#pragma unroll
            for (int q = 0; q < 4; ++q) { a[q] = __shfl(w, j2 + q); si[q] = __shfl(s, j2 + q); }
#pragma unroll
            for (int q = 0; q < 4; ++q) hv[q] = __half2float(h[(size_t)si[q] * CH + lane]);
#pragma unroll
            for (int q = 0; q < 4; ++q) acc = fmaf(a[q], hv[q], acc);
        }
        for (; j2 < cnt; ++j2) {
            const float a = __shfl(w, j2);
            const int ss = __shfl(s, j2);
            acc = fmaf(a, __half2float(h[(size_t)ss * CH + lane]), acc);
        }
    }
#pragma unroll
    for (int off = 32; off; off >>= 1) wsum += __shfl_xor(wsum, off);
    acc /= fmaxf(wsum, 1e-9f);
    const float v = acc + b[lane];
    out[(size_t)node * CH + lane] = (v > 0.f) ? v : 0.3f * v;
}

extern "C" void kernel_launch(void* const* d_in, const int* in_sizes, int n_in,
                              void* d_out, int out_size, void* d_ws, size_t ws_size,
                              hipStream_t stream) {
    const float* x     = (const float*)d_in[0];
    const float* W     = (const float*)d_in[1];
    const float* a_src = (const float*)d_in[2];
    const float* a_dst = (const float*)d_in[3];
    const float* b     = (const float*)d_in[4];
    const int* esrc    = (const int*)d_in[5];
    const int* edst    = (const int*)d_in[6];
    float* out = (float*)d_out;

    char* ws = (char*)d_ws;
    __half* h                = (__half*)(ws + OFF_H);
    float* ssrc              = (float*)(ws + OFF_SSRC);
    float* sdst              = (float*)(ws + OFF_SDST);
    unsigned int* hist       = (unsigned int*)(ws + OFF_HIST);
    unsigned int* bintot     = (unsigned int*)(ws + OFF_BTOT);
    unsigned int* cb         = (unsigned int*)(ws + OFF_CB);
    int* row_ptr             = (int*)(ws + OFF_ROWPTR);
    unsigned int* buck       = (unsigned int*)(ws + OFF_BUCK);
    unsigned short* src_perm = (unsigned short*)(ws + OFF_SPERM);

    k_feat<<<FT_BLKS, 256, 0, stream>>>(x, W, a_src, a_dst, edst, h, ssrc, sdst, hist);
    k_bintot<<<NB, 256, 0, stream>>>(hist, bintot);
    k_rewrite<<<NB, 256, 0, stream>>>(bintot, hist, cb);
    k_scatter<<<NCHK, 256, 0, stream>>>(esrc, edst, hist, buck);
    k_csr<<<NB, 256, 0, stream>>>(buck, cb, row_ptr, src_perm);
    k_node_agg<<<N_NODES / 4, 256, 0, stream>>>(src_perm, row_ptr, ssrc, sdst, h, b, out);
}